// Round 2
// baseline (20871.411 us; speedup 1.0000x reference)
//
#include <hip/hip_runtime.h>
#include <cstdint>
#include <cstddef>

#define BATCH 32
#define SEQT  512
#define EMBED 1024
#define HID   1024
#define G3    3072   // 3*HID

__device__ __forceinline__ float sigm(float x) { return 1.0f / (1.0f + expf(-x)); }

// bf16 <-> f32 helpers (manual, RNE on store)
__device__ __forceinline__ float b2f(unsigned short s) {
    return __uint_as_float(((uint32_t)s) << 16);
}
__device__ __forceinline__ unsigned short f2b(float f) {
    uint32_t u = __float_as_uint(f);
    uint32_t r = (u + 0x7FFFu + ((u >> 16) & 1u)) >> 16;
    return (unsigned short)r;
}

// ---------------------------------------------------------------------------
// Generic C[m][n] = f( sum_k A[m][k]*W[n][k] + ... )
// ABF16: A is bf16 (else f32). W always f32 [N][K].
// MODE 0: C f32  = acc + bias[n]
// MODE 1: C bf16 = tanh(acc + bias[n] + ctx[m>>9][n])
// MODE 2: C bf16 = acc + bias[n]
// GATEA: A element (m,k) scaled by (1 + gate[m>>9][k]) at load.
// Tile 128x128, BK=8, 256 threads, 8x8 per thread. M,N,K multiples of 128/8.
// ---------------------------------------------------------------------------
template<bool ABF16, int MODE, bool GATEA>
__global__ __launch_bounds__(256) void gemm_bt(
    const void* __restrict__ Av, const float* __restrict__ W,
    const float* __restrict__ bias, const float* __restrict__ ctx,
    const float* __restrict__ gate, void* __restrict__ Cv, int N, int K)
{
    __shared__ float As[8][128];
    __shared__ float Bs[8][128];

    const int tid = threadIdx.x;
    const int tx = tid & 15;
    const int ty = tid >> 4;
    const int m0 = blockIdx.y * 128;
    const int n0 = blockIdx.x * 128;

    float acc[8][8];
#pragma unroll
    for (int i = 0; i < 8; i++)
#pragma unroll
        for (int j = 0; j < 8; j++) acc[i][j] = 0.0f;

    const int lrow = tid >> 1;          // 0..127
    const int lk   = (tid & 1) * 4;     // 0 or 4
    const float* Wp = W + (size_t)(n0 + lrow) * K + lk;
    const size_t arow = (size_t)(m0 + lrow) * K + lk;
    const float* Af = (const float*)Av;
    const unsigned short* Ah = (const unsigned short*)Av;
    const float* grow = GATEA ? (gate + (size_t)((m0 + lrow) >> 9) * HID + lk) : nullptr;

    for (int kt = 0; kt < K; kt += 8) {
        float a4[4];
        if (ABF16) {
            short4 v = *(const short4*)(Ah + arow + kt);
            a4[0] = b2f((unsigned short)v.x); a4[1] = b2f((unsigned short)v.y);
            a4[2] = b2f((unsigned short)v.z); a4[3] = b2f((unsigned short)v.w);
        } else {
            float4 v = *(const float4*)(Af + arow + kt);
            a4[0] = v.x; a4[1] = v.y; a4[2] = v.z; a4[3] = v.w;
        }
        if (GATEA) {
            float4 g = *(const float4*)(grow + kt);
            a4[0] *= 1.0f + g.x; a4[1] *= 1.0f + g.y;
            a4[2] *= 1.0f + g.z; a4[3] *= 1.0f + g.w;
        }
        float4 wv = *(const float4*)(Wp + kt);
        __syncthreads();
        As[lk + 0][lrow] = a4[0]; As[lk + 1][lrow] = a4[1];
        As[lk + 2][lrow] = a4[2]; As[lk + 3][lrow] = a4[3];
        Bs[lk + 0][lrow] = wv.x; Bs[lk + 1][lrow] = wv.y;
        Bs[lk + 2][lrow] = wv.z; Bs[lk + 3][lrow] = wv.w;
        __syncthreads();
#pragma unroll
        for (int k = 0; k < 8; k++) {
            float4 a0 = *(const float4*)&As[k][ty * 4];
            float4 a1 = *(const float4*)&As[k][64 + ty * 4];
            float4 b0 = *(const float4*)&Bs[k][tx * 4];
            float4 b1 = *(const float4*)&Bs[k][64 + tx * 4];
            float am[8] = {a0.x, a0.y, a0.z, a0.w, a1.x, a1.y, a1.z, a1.w};
            float bn[8] = {b0.x, b0.y, b0.z, b0.w, b1.x, b1.y, b1.z, b1.w};
#pragma unroll
            for (int i = 0; i < 8; i++)
#pragma unroll
                for (int j = 0; j < 8; j++) acc[i][j] += am[i] * bn[j];
        }
    }

    // epilogue
#pragma unroll
    for (int i = 0; i < 8; i++) {
        const int mr = (i < 4) ? (ty * 4 + i) : (64 + ty * 4 + i - 4);
        const size_t m = (size_t)(m0 + mr);
        const int b = (int)(m >> 9);
#pragma unroll
        for (int jh = 0; jh < 2; jh++) {
            const int nc = n0 + (jh ? (64 + tx * 4) : (tx * 4));
            float vals[4];
#pragma unroll
            for (int q = 0; q < 4; q++) {
                const int aj = jh ? (4 + q) : q;
                float val = acc[i][aj] + bias[nc + q];
                if (MODE == 1) val = tanhf(val + ctx[(size_t)b * HID + nc + q]);
                vals[q] = val;
            }
            if (MODE == 0) {
                float4 v; v.x = vals[0]; v.y = vals[1]; v.z = vals[2]; v.w = vals[3];
                *(float4*)((float*)Cv + m * (size_t)N + nc) = v;
            } else {
                short4 sv;
                sv.x = (short)f2b(vals[0]); sv.y = (short)f2b(vals[1]);
                sv.z = (short)f2b(vals[2]); sv.w = (short)f2b(vals[3]);
                *(short4*)((unsigned short*)Cv + m * (size_t)N + nc) = sv;
            }
        }
    }
}

// ---------------------------------------------------------------------------
// gate[b][j] = sigmoid( sum_k ctx[b][k] * Wg[j][k] + bg[j] )    (all f32)
// ---------------------------------------------------------------------------
__global__ __launch_bounds__(256) void gate_kernel(
    const float* __restrict__ ctx, const float* __restrict__ Wg,
    const float* __restrict__ bg, float* __restrict__ gate)
{
    const int j = blockIdx.x * 256 + threadIdx.x;
    const int b = blockIdx.y;
    const float4* cp = (const float4*)(ctx + (size_t)b * HID);
    const float4* wp = (const float4*)(Wg + (size_t)j * HID);
    float acc = 0.0f;
#pragma unroll 4
    for (int k = 0; k < HID / 4; k++) {
        float4 c = cp[k], w = wp[k];
        acc += c.x * w.x + c.y * w.y + c.z * w.z + c.w * w.w;
    }
    gate[(size_t)b * HID + j] = sigm(acc + bg[j]);
}

// ---------------------------------------------------------------------------
// f32 -> bf16 elementwise (for Whh conversion). n multiple of 1024.
// ---------------------------------------------------------------------------
__global__ __launch_bounds__(256) void f2b_kernel(
    const float* __restrict__ in, unsigned short* __restrict__ out, int n)
{
    const int i = (blockIdx.x * 256 + threadIdx.x) * 4;
    if (i < n) {
        float4 v = *(const float4*)(in + i);
        short4 s;
        s.x = (short)f2b(v.x); s.y = (short)f2b(v.y);
        s.z = (short)f2b(v.z); s.w = (short)f2b(v.w);
        *(short4*)(out + i) = s;
    }
}

// ---------------------------------------------------------------------------
// One GRU time step (torch gate order r,z,n). bf16 storage, f32 accum.
// xg: [B][T][3H] bf16; hbuf: [B][T][H] bf16; Whh bf16 [3H][H]; bhh f32.
// 256 blocks x 256 threads; wave w handles j = bid*4+w;
// lane = 32 b x 2 k-halves, shfl_xor(32) reduce.
// ---------------------------------------------------------------------------
__global__ __launch_bounds__(256) void gru_step(
    const unsigned short* __restrict__ Whh, const float* __restrict__ bhh,
    const unsigned short* __restrict__ xg, unsigned short* __restrict__ hbuf,
    int t)
{
    const int tid = threadIdx.x;
    const int lane = tid & 63;
    const int w = tid >> 6;                 // 0..3
    const int j = blockIdx.x * 4 + w;       // 0..1023
    const int b = lane & 31;
    const int kh = lane >> 5;               // 0/1

    float ar = 0.0f, az = 0.0f, an = 0.0f;

    if (t > 0) {
        const unsigned short* hrow = hbuf + ((size_t)b * SEQT + (t - 1)) * HID + kh * 512;
        const unsigned short* wr = Whh + (size_t)j * HID + kh * 512;
        const unsigned short* wz = wr + (size_t)HID * HID;
        const unsigned short* wn = wz + (size_t)HID * HID;
#pragma unroll 4
        for (int k = 0; k < 512; k += 4) {
            short4 h4 = *(const short4*)(hrow + k);
            short4 r4 = *(const short4*)(wr + k);
            short4 z4 = *(const short4*)(wz + k);
            short4 n4 = *(const short4*)(wn + k);
            float h0 = b2f((unsigned short)h4.x), h1 = b2f((unsigned short)h4.y);
            float h2 = b2f((unsigned short)h4.z), h3 = b2f((unsigned short)h4.w);
            ar += b2f((unsigned short)r4.x) * h0 + b2f((unsigned short)r4.y) * h1
                + b2f((unsigned short)r4.z) * h2 + b2f((unsigned short)r4.w) * h3;
            az += b2f((unsigned short)z4.x) * h0 + b2f((unsigned short)z4.y) * h1
                + b2f((unsigned short)z4.z) * h2 + b2f((unsigned short)z4.w) * h3;
            an += b2f((unsigned short)n4.x) * h0 + b2f((unsigned short)n4.y) * h1
                + b2f((unsigned short)n4.z) * h2 + b2f((unsigned short)n4.w) * h3;
        }
    }

    ar += __shfl_xor(ar, 32);
    az += __shfl_xor(az, 32);
    an += __shfl_xor(an, 32);

    if (kh == 0) {
        float hprev = 0.0f;
        if (t > 0) hprev = b2f(hbuf[((size_t)b * SEQT + (t - 1)) * HID + j]);
        const size_t xo = ((size_t)b * SEQT + t) * G3;
        const float xr = b2f(xg[xo + j]);
        const float xz = b2f(xg[xo + HID + j]);
        const float xn = b2f(xg[xo + 2 * HID + j]);
        const float r = sigm(xr + ar + bhh[j]);
        const float z = sigm(xz + az + bhh[HID + j]);
        const float n = tanhf(xn + r * (an + bhh[2 * HID + j]));
        const float h = (1.0f - z) * n + z * hprev;
        hbuf[((size_t)b * SEQT + t) * HID + j] = f2b(h);
    }
}

// ---------------------------------------------------------------------------
// Diagnostic fallback: out[0] = ws_size in MiB, rest 0. (Only if ws too small.)
// ---------------------------------------------------------------------------
__global__ __launch_bounds__(256) void diag_kernel(float* __restrict__ out,
                                                   int n, float code)
{
    for (int i = blockIdx.x * 256 + threadIdx.x; i < n; i += gridDim.x * 256)
        out[i] = (i == 0) ? code : 0.0f;
}

// ---------------------------------------------------------------------------
extern "C" void kernel_launch(void* const* d_in, const int* in_sizes, int n_in,
                              void* d_out, int out_size, void* d_ws, size_t ws_size,
                              hipStream_t stream)
{
    const float* x      = (const float*)d_in[0];
    const float* ctx    = (const float*)d_in[1];
    const float* W_in   = (const float*)d_in[2];
    const float* b_in   = (const float*)d_in[3];
    const float* Wih0   = (const float*)d_in[4];
    const float* Whh0   = (const float*)d_in[5];
    const float* bih0   = (const float*)d_in[6];
    const float* bhh0   = (const float*)d_in[7];
    const float* Wih1   = (const float*)d_in[8];
    const float* Whh1   = (const float*)d_in[9];
    const float* bih1   = (const float*)d_in[10];
    const float* bhh1   = (const float*)d_in[11];
    const float* W_out  = (const float*)d_in[12];
    const float* b_out  = (const float*)d_in[13];
    const float* W_gate = (const float*)d_in[14];
    const float* b_gate = (const float*)d_in[15];
    float* out = (float*)d_out;

    // workspace layout (bf16 intermediates), total ~140.3 MiB:
    //   region0: xg        [B*T][3H] bf16 = 96 MiB
    //   region1: mixed/h1/h2 [B*T][H] bf16 = 32 MiB  (sequential reuse)
    //   whh0b, whh1b: bf16 copies of Whh  = 6 MiB each
    //   gate: [B][H] f32 = 128 KiB
    const size_t REG0 = (size_t)16384 * 3072 * 2;
    const size_t REG1 = (size_t)16384 * 1024 * 2;
    const size_t WB   = (size_t)3072 * 1024 * 2;
    const size_t GATE = (size_t)32 * 1024 * 4;
    const size_t need = REG0 + REG1 + 2 * WB + GATE;

    if (ws_size < need) {
        // don't fault — report ws_size via out[0] so the bench reveals it
        diag_kernel<<<2048, 256, 0, stream>>>(out, out_size,
                                              (float)(ws_size >> 20));
        return;
    }

    char* ws = (char*)d_ws;
    unsigned short* xgbuf = (unsigned short*)ws;
    unsigned short* hbuf  = (unsigned short*)(ws + REG0);
    unsigned short* whh0b = (unsigned short*)(ws + REG0 + REG1);
    unsigned short* whh1b = (unsigned short*)(ws + REG0 + REG1 + WB);
    float*          gate  = (float*)(ws + REG0 + REG1 + 2 * WB);

    // Whh -> bf16
    f2b_kernel<<<3072, 256, 0, stream>>>(Whh0, whh0b, 3072 * 1024);
    f2b_kernel<<<3072, 256, 0, stream>>>(Whh1, whh1b, 3072 * 1024);

    // gate = sigmoid(ctx @ W_gate^T + b_gate)
    gate_kernel<<<dim3(4, 32), 256, 0, stream>>>(ctx, W_gate, b_gate, gate);

    // mixed = tanh(x @ W_in^T + b_in + ctx[b])  -> hbuf (bf16)
    gemm_bt<false, 1, false><<<dim3(8, 128), 256, 0, stream>>>(
        x, W_in, b_in, ctx, nullptr, hbuf, 1024, 1024);

    // xg0 = mixed @ Wih0^T + bih0 -> xgbuf (bf16)
    gemm_bt<true, 2, false><<<dim3(24, 128), 256, 0, stream>>>(
        hbuf, Wih0, bih0, nullptr, nullptr, xgbuf, 3072, 1024);

    // GRU layer 0 scan: h1 series overwrites hbuf (mixed already consumed)
    for (int t = 0; t < SEQT; t++)
        gru_step<<<256, 256, 0, stream>>>(whh0b, bhh0, xgbuf, hbuf, t);

    // xg1 = h1 @ Wih1^T + bih1 -> xgbuf (reuse)
    gemm_bt<true, 2, false><<<dim3(24, 128), 256, 0, stream>>>(
        hbuf, Wih1, bih1, nullptr, nullptr, xgbuf, 3072, 1024);

    // GRU layer 1 scan: h2 series overwrites hbuf (h1 already consumed)
    for (int t = 0; t < SEQT; t++)
        gru_step<<<256, 256, 0, stream>>>(whh1b, bhh1, xgbuf, hbuf, t);

    // out = (h2 * (1+gate)) @ W_out^T + b_out   (gate fused into A-load)
    gemm_bt<true, 0, true><<<dim3(8, 128), 256, 0, stream>>>(
        hbuf, W_out, b_out, nullptr, gate, out, 1024, 1024);
}